// Round 4
// baseline (546.302 us; speedup 1.0000x reference)
//
#include <hip/hip_runtime.h>

typedef unsigned short u16;
typedef short s16x8 __attribute__((ext_vector_type(8)));
typedef float f32x4 __attribute__((ext_vector_type(4)));
typedef u16 u16x4 __attribute__((ext_vector_type(4)));

#define NN 50000
#define NE 300000
#define HH 256
#define NCHUNK 196

__device__ __forceinline__ float b2f(u16 u) {
  union { float f; unsigned int i; } v; v.i = ((unsigned int)u) << 16; return v.f;
}
__device__ __forceinline__ u16 f2b(float f) {
  union { float f; unsigned int i; } v; v.f = f;
  unsigned int u = v.i;
  unsigned int r = (u + 0x7fffu + ((u >> 16) & 1u)) >> 16;
  return (u16)r;
}
__device__ __forceinline__ float lrelu(float x) { return x > 0.f ? x : 0.2f * x; }

#define GLOAD_LDS16(SRC, DST)                                                   \
  __builtin_amdgcn_global_load_lds(                                             \
      (const __attribute__((address_space(1))) void*)(SRC),                     \
      (__attribute__((address_space(3))) void*)(DST), 16, 0, 0)

// swizzle slot for 64B rows (4x16B chunks): 2-way-free bank pattern
__device__ __forceinline__ int swz4(int r) { return (r + (r >> 2)) & 3; }

// ---------------------------------------------------------------------------
// xb = bf16(x); g_sum[c] += column sums
__global__ void xprep(const float* __restrict__ x, u16* __restrict__ xb,
                      float* __restrict__ g_sum) {
  int tid = threadIdx.x, lane = tid & 63, w = tid >> 6;
  f32x4 part = {0.f, 0.f, 0.f, 0.f};
  for (int r = blockIdx.x * 4 + w; r < NN; r += 4096) {
    f32x4 v = *(const f32x4*)(x + (size_t)r * HH + lane * 4);
    u16x4 o;
#pragma unroll
    for (int k = 0; k < 4; ++k) o[k] = f2b(v[k]);
    *(u16x4*)(xb + (size_t)r * HH + lane * 4) = o;
    part += v;
  }
  __shared__ f32x4 sh[256];
  sh[tid] = part;
  __syncthreads();
  if (tid < 64) {
    f32x4 t = sh[tid] + sh[tid + 64] + sh[tid + 128] + sh[tid + 192];
#pragma unroll
    for (int k = 0; k < 4; ++k) atomicAdd(&g_sum[lane * 4 + k], t[k]);
  }
}

// 8 weight transposes: WT[z][n][k] = bf16(src_z[k][n])
__global__ void transpose_all(const float* __restrict__ Wg, const float* __restrict__ Wsm,
                              const float* __restrict__ Wf, u16* __restrict__ WT) {
  __shared__ float tile[32][33];
  int z = blockIdx.z;
  const float* src = (z < 3) ? (Wg + (size_t)z * 65536)
                   : (z < 7) ? (Wsm + (size_t)(z - 3) * 65536) : Wf;
  u16* dst = WT + (size_t)z * 65536;
  int tx = threadIdx.x, ty = threadIdx.y;
  int bx = blockIdx.x, by = blockIdx.y;
#pragma unroll
  for (int j = 0; j < 32; j += 8)
    tile[ty + j][tx] = src[(size_t)(by * 32 + ty + j) * 256 + bx * 32 + tx];
  __syncthreads();
#pragma unroll
  for (int j = 0; j < 32; j += 8)
    dst[(size_t)(bx * 32 + ty + j) * 256 + by * 32 + tx] = f2b(tile[tx][ty + j]);
}

__global__ void selector_kernel(const float* __restrict__ g_sum,
                                const float* __restrict__ W1, const float* __restrict__ b1,
                                const float* __restrict__ W2, const float* __restrict__ b2,
                                float* __restrict__ sw) {
  __shared__ float gg[256];
  __shared__ float hid[128];
  __shared__ float lg[4];
  int t = threadIdx.x;  // 128
  gg[t] = g_sum[t] * (1.0f / NN);
  gg[t + 128] = g_sum[t + 128] * (1.0f / NN);
  __syncthreads();
  float a = 0.f;
  for (int c = 0; c < 256; ++c) a += gg[c] * W1[c * 128 + t];
  a += b1[t];
  hid[t] = a > 0.f ? a : 0.f;
  __syncthreads();
  if (t < 4) {
    float s = 0.f;
    for (int j = 0; j < 128; ++j) s += hid[j] * W2[j * 4 + t];
    lg[t] = s + b2[t];
  }
  __syncthreads();
  if (t == 0) {
    float m = fmaxf(fmaxf(lg[0], lg[1]), fmaxf(lg[2], lg[3]));
    float e0 = __expf(lg[0] - m), e1 = __expf(lg[1] - m);
    float e2 = __expf(lg[2] - m), e3 = __expf(lg[3] - m);
    float inv = 1.0f / (e0 + e1 + e2 + e3);
    sw[0] = e0 * inv; sw[1] = e1 * inv; sw[2] = e2 * inv; sw[3] = e3 * inv;
  }
}

// ---------------------------------------------------------------------------
__global__ void detect_kernel(const int* __restrict__ ei_raw, int* __restrict__ flag) {
  int t = threadIdx.x;
  int nz = 0;
  for (int k = t; k < 1024; k += 256) nz |= (ei_raw[2 * k + 1] != 0);
  if (nz) atomicOr(flag, 1);
}

__global__ void norm_edges(const int* __restrict__ ei_raw, const int* __restrict__ ea_raw,
                           const int* __restrict__ flag, int* __restrict__ srcE,
                           int* __restrict__ dstE, int* __restrict__ attrE) {
  int e = blockIdx.x * 256 + threadIdx.x;
  if (e >= NE) return;
  if (*flag) {
    srcE[e] = ei_raw[e];
    dstE[e] = ei_raw[NE + e];
    attrE[e] = ea_raw[e];
  } else {
    srcE[e] = ei_raw[2 * e];
    dstE[e] = ei_raw[2 * NE + 2 * e];
    attrE[e] = ea_raw[2 * e];
  }
}

__global__ void hist_kernel(const int* __restrict__ dstE, const int* __restrict__ attrE,
                            int* __restrict__ counts) {
  int e = blockIdx.x * 256 + threadIdx.x;
  if (e < NE) {
    int a = attrE[e];
    if ((unsigned)a < 3u) atomicAdd(&counts[a * NN + dstE[e]], 1);
  }
}

__global__ void scan1(const int* __restrict__ counts, int* __restrict__ offs,
                      int* __restrict__ bsum) {
  int b = blockIdx.y, c = blockIdx.x, t = threadIdx.x;
  int idx = c * 256 + t;
  int v = (idx < NN) ? counts[b * NN + idx] : 0;
  __shared__ int sh[256];
  sh[t] = v;
  __syncthreads();
  for (int o = 1; o < 256; o <<= 1) {
    int add = (t >= o) ? sh[t - o] : 0;
    __syncthreads();
    sh[t] += add;
    __syncthreads();
  }
  int incl = sh[t];
  if (idx < NN) offs[b * (NN + 1) + idx] = incl - v;
  if (t == 255) bsum[b * NCHUNK + c] = incl;
}

__global__ void scan2(const int* __restrict__ bsum, int* __restrict__ bpre,
                      int* __restrict__ offs) {
  int t = threadIdx.x;
  if (t < 3) {
    int run = 0;
    for (int c = 0; c < NCHUNK; ++c) { bpre[t * NCHUNK + c] = run; run += bsum[t * NCHUNK + c]; }
    offs[t * (NN + 1) + NN] = run;
  }
}

__global__ void scan3(const int* __restrict__ bpre, int* __restrict__ offs,
                      int* __restrict__ cur) {
  int b = blockIdx.y, c = blockIdx.x;
  int idx = c * 256 + threadIdx.x;
  if (idx < NN) {
    int val = offs[b * (NN + 1) + idx] + bpre[b * NCHUNK + c];
    offs[b * (NN + 1) + idx] = val;
    cur[b * NN + idx] = val;
  }
}

__global__ void scatter_kernel(const int* __restrict__ srcE, const int* __restrict__ dstE,
                               const int* __restrict__ attrE, int* __restrict__ cur,
                               int* __restrict__ elist) {
  int e = blockIdx.x * 256 + threadIdx.x;
  if (e < NE) {
    int a = attrE[e];
    if ((unsigned)a < 3u) {
      int p = atomicAdd(&cur[a * NN + dstE[e]], 1);
      elist[a * NE + p] = srcE[e];
    }
  }
}

// ---------------------------------------------------------------------------
// Pipelined GEMM core: BM=64, BN=256, BK=32, double-buffered LDS.
// Tile rows are 64B (32 bf16); swizzle chunk-slot with swz4(row).
__device__ __forceinline__ void stageA(const u16* __restrict__ A, int strideA, int coloff,
                                       int row0, int M, int k0, char* ldsbase,
                                       int lane, int wid) {
  int off = wid * 1024 + lane * 16;
  int r = off >> 6, cb = off & 63;
  int cbs = cb ^ (swz4(r) << 4);
  int ga = row0 + r; if (ga > M - 1) ga = M - 1;
  GLOAD_LDS16(A + (size_t)ga * strideA + coloff + k0 + (cbs >> 1), ldsbase + wid * 1024);
}

__device__ __forceinline__ void stageB(const u16* __restrict__ BT, int k0, char* ldsbase,
                                       int lane, int wid) {
#pragma unroll
  for (int j = 0; j < 4; ++j) {
    int base = (j * 4 + wid) * 1024;
    int off = base + lane * 16;
    int r = off >> 6, cb = off & 63;
    int cbs = cb ^ (swz4(r) << 4);
    GLOAD_LDS16(BT + (size_t)r * 256 + k0 + (cbs >> 1), ldsbase + base);
  }
}

__device__ __forceinline__ void kstep(const char* __restrict__ la, const char* __restrict__ lb,
                                      int lane, int wc, f32x4 acc[4][4]) {
  int kb = (lane >> 4) * 16;
  s16x8 af[4], bfr[4];
#pragma unroll
  for (int i = 0; i < 4; ++i) {
    int rowA = i * 16 + (lane & 15);
    af[i] = *(const s16x8*)(la + rowA * 64 + (kb ^ (swz4(rowA) << 4)));
    int rowB = wc * 64 + i * 16 + (lane & 15);
    bfr[i] = *(const s16x8*)(lb + rowB * 64 + (kb ^ (swz4(rowB) << 4)));
  }
#pragma unroll
  for (int i = 0; i < 4; ++i)
#pragma unroll
    for (int n = 0; n < 4; ++n)
      acc[i][n] = __builtin_amdgcn_mfma_f32_16x16x32_bf16(af[i], bfr[n], acc[i][n], 0, 0, 0);
}

#define GEMM_SHARED                                                             \
  __shared__ __align__(16) u16 lds_a[2][64 * 32];                               \
  __shared__ __align__(16) u16 lds_b[2][256 * 32];                              \
  __shared__ float redS[4][64];                                                 \
  __shared__ float redQ[4][64];                                                 \
  __shared__ float muL[64];                                                     \
  __shared__ float rsL[64];

#define RUN_KLOOP(APTR, ASTR, ACOFF, BTPTR)                                     \
  {                                                                             \
    stageA(APTR, ASTR, ACOFF, row0, M, 0, (char*)lds_a[0], lane, wid);          \
    stageB(BTPTR, 0, (char*)lds_b[0], lane, wid);                               \
    __syncthreads();                                                            \
    for (int t = 0; t < 8; ++t) {                                               \
      int cu = t & 1;                                                           \
      if (t < 7) {                                                              \
        stageA(APTR, ASTR, ACOFF, row0, M, (t + 1) * 32, (char*)lds_a[cu ^ 1],  \
               lane, wid);                                                      \
        stageB(BTPTR, (t + 1) * 32, (char*)lds_b[cu ^ 1], lane, wid);           \
      }                                                                         \
      kstep((const char*)lds_a[cu], (const char*)lds_b[cu], lane, wid, acc);    \
      __syncthreads();                                                          \
    }                                                                           \
  }

// h-GEMM (batched over 3 branches via blockIdx.y) + fused s/d row dots.
__global__ __launch_bounds__(256) void mgemm_h(
    const u16* __restrict__ xb, const u16* __restrict__ WT,
    const float* __restrict__ asrc, const float* __restrict__ adst,
    u16* __restrict__ h, float* __restrict__ s_arr, float* __restrict__ d_arr, int M) {
  GEMM_SHARED
  int tid = threadIdx.x, lane = tid & 63, wid = tid >> 6;
  int row0 = blockIdx.x * 64;
  int b = blockIdx.y;
  const u16* BT = WT + (size_t)b * 65536;
  const float* av = asrc + b * 256;
  const float* dvec = adst + b * 256;

  f32x4 acc[4][4] = {};
  RUN_KLOOP(xb, 256, 0, BT)

  int colbase = wid * 64 + (lane & 15);
  float a4[4], dd4[4];
#pragma unroll
  for (int n = 0; n < 4; ++n) { a4[n] = av[colbase + n * 16]; dd4[n] = dvec[colbase + n * 16]; }
#pragma unroll
  for (int i = 0; i < 4; ++i)
#pragma unroll
    for (int r = 0; r < 4; ++r) {
      float sp = 0.f, dp = 0.f;
#pragma unroll
      for (int n = 0; n < 4; ++n) { float v = acc[i][n][r]; sp += v * a4[n]; dp += v * dd4[n]; }
#pragma unroll
      for (int m = 1; m < 16; m <<= 1) { sp += __shfl_xor(sp, m); dp += __shfl_xor(dp, m); }
      if ((lane & 15) == 0) {
        int rl = i * 16 + (lane >> 4) * 4 + r;
        redS[wid][rl] = sp; redQ[wid][rl] = dp;
      }
    }
  __syncthreads();
  if (tid < 64 && row0 + tid < M) {
    s_arr[(size_t)b * NN + row0 + tid] = redS[0][tid] + redS[1][tid] + redS[2][tid] + redS[3][tid];
    d_arr[(size_t)b * NN + row0 + tid] = redQ[0][tid] + redQ[1][tid] + redQ[2][tid] + redQ[3][tid];
  }
#pragma unroll
  for (int i = 0; i < 4; ++i)
#pragma unroll
    for (int r = 0; r < 4; ++r) {
      int row = row0 + i * 16 + (lane >> 4) * 4 + r;
      if (row < M)
#pragma unroll
        for (int n = 0; n < 4; ++n)
          h[(size_t)row * 768 + b * 256 + colbase + n * 16] = f2b(acc[i][n][r]);
    }
}

// Mega-Ws: loops 4 branches (A = xiall slices / xb), LN+scale, accumulate comb in regs.
__global__ __launch_bounds__(256) void mgemm_ws(
    const u16* __restrict__ xiall, const u16* __restrict__ xb,
    const u16* __restrict__ WT, const float* __restrict__ bs,
    const float* __restrict__ gs, const float* __restrict__ betas,
    const float* __restrict__ sw, u16* __restrict__ comb, int M) {
  GEMM_SHARED
  int tid = threadIdx.x, lane = tid & 63, wid = tid >> 6;
  int row0 = blockIdx.x * 64;
  int colbase = wid * 64 + (lane & 15);

  f32x4 cacc[4][4] = {};
  const u16* Ab[4] = {xiall, xiall, xiall, xb};
  const int sAb[4] = {768, 768, 768, 256};
  const int cofb[4] = {0, 256, 512, 0};

#pragma unroll
  for (int b = 0; b < 4; ++b) {
    const u16* BT = WT + (size_t)(3 + b) * 65536;
    const float* bias = bs + b * 256;
    const float* gv = gs + b * 256;
    const float* bev = betas + b * 256;
    f32x4 acc[4][4] = {};
    RUN_KLOOP(Ab[b], sAb[b], cofb[b], BT)

    float bv4[4], g4[4], be4[4];
#pragma unroll
    for (int n = 0; n < 4; ++n) {
      bv4[n] = bias[colbase + n * 16];
      g4[n] = gv[colbase + n * 16];
      be4[n] = bev[colbase + n * 16];
    }
#pragma unroll
    for (int i = 0; i < 4; ++i)
#pragma unroll
      for (int n = 0; n < 4; ++n)
#pragma unroll
        for (int r = 0; r < 4; ++r) acc[i][n][r] += bv4[n];
#pragma unroll
    for (int i = 0; i < 4; ++i)
#pragma unroll
      for (int r = 0; r < 4; ++r) {
        float s = 0.f, q = 0.f;
#pragma unroll
        for (int n = 0; n < 4; ++n) { float v = acc[i][n][r]; s += v; q += v * v; }
#pragma unroll
        for (int m = 1; m < 16; m <<= 1) { s += __shfl_xor(s, m); q += __shfl_xor(q, m); }
        if ((lane & 15) == 0) {
          int rl = i * 16 + (lane >> 4) * 4 + r;
          redS[wid][rl] = s; redQ[wid][rl] = q;
        }
      }
    __syncthreads();
    if (tid < 64) {
      float s = redS[0][tid] + redS[1][tid] + redS[2][tid] + redS[3][tid];
      float q = redQ[0][tid] + redQ[1][tid] + redQ[2][tid] + redQ[3][tid];
      float mu = s * (1.0f / HH);
      float var = q * (1.0f / HH) - mu * mu;
      muL[tid] = mu;
      rsL[tid] = rsqrtf(var + 1e-5f);
    }
    __syncthreads();
    float w = sw[b];
#pragma unroll
    for (int i = 0; i < 4; ++i)
#pragma unroll
      for (int r = 0; r < 4; ++r) {
        int rl = i * 16 + (lane >> 4) * 4 + r;
        float mu = muL[rl], rs = rsL[rl];
#pragma unroll
        for (int n = 0; n < 4; ++n) {
          float t = (acc[i][n][r] - mu) * rs * g4[n] + be4[n];
          cacc[i][n][r] += w * (t > 0.f ? t : 0.f);
        }
      }
    __syncthreads();  // protect muL/redS reuse by next branch
  }
#pragma unroll
  for (int i = 0; i < 4; ++i)
#pragma unroll
    for (int r = 0; r < 4; ++r) {
      int row = row0 + i * 16 + (lane >> 4) * 4 + r;
      if (row < M)
#pragma unroll
        for (int n = 0; n < 4; ++n)
          comb[(size_t)row * 256 + colbase + n * 16] = f2b(cacc[i][n][r]);
    }
}

// Final: out = relu(LN(comb @ Wf + bf)) as f32
__global__ __launch_bounds__(256) void mgemm_fin(
    const u16* __restrict__ comb, const u16* __restrict__ BT,
    const float* __restrict__ bias, const float* __restrict__ gv,
    const float* __restrict__ bev, float* __restrict__ outf, int M) {
  GEMM_SHARED
  int tid = threadIdx.x, lane = tid & 63, wid = tid >> 6;
  int row0 = blockIdx.x * 64;
  int colbase = wid * 64 + (lane & 15);

  f32x4 acc[4][4] = {};
  RUN_KLOOP(comb, 256, 0, BT)

  float bv4[4], g4[4], be4[4];
#pragma unroll
  for (int n = 0; n < 4; ++n) {
    bv4[n] = bias[colbase + n * 16];
    g4[n] = gv[colbase + n * 16];
    be4[n] = bev[colbase + n * 16];
  }
#pragma unroll
  for (int i = 0; i < 4; ++i)
#pragma unroll
    for (int n = 0; n < 4; ++n)
#pragma unroll
      for (int r = 0; r < 4; ++r) acc[i][n][r] += bv4[n];
#pragma unroll
  for (int i = 0; i < 4; ++i)
#pragma unroll
    for (int r = 0; r < 4; ++r) {
      float s = 0.f, q = 0.f;
#pragma unroll
      for (int n = 0; n < 4; ++n) { float v = acc[i][n][r]; s += v; q += v * v; }
#pragma unroll
      for (int m = 1; m < 16; m <<= 1) { s += __shfl_xor(s, m); q += __shfl_xor(q, m); }
      if ((lane & 15) == 0) {
        int rl = i * 16 + (lane >> 4) * 4 + r;
        redS[wid][rl] = s; redQ[wid][rl] = q;
      }
    }
  __syncthreads();
  if (tid < 64) {
    float s = redS[0][tid] + redS[1][tid] + redS[2][tid] + redS[3][tid];
    float q = redQ[0][tid] + redQ[1][tid] + redQ[2][tid] + redQ[3][tid];
    float mu = s * (1.0f / HH);
    float var = q * (1.0f / HH) - mu * mu;
    muL[tid] = mu;
    rsL[tid] = rsqrtf(var + 1e-5f);
  }
  __syncthreads();
#pragma unroll
  for (int i = 0; i < 4; ++i)
#pragma unroll
    for (int r = 0; r < 4; ++r) {
      int rl = i * 16 + (lane >> 4) * 4 + r;
      int row = row0 + rl;
      if (row >= M) continue;
      float mu = muL[rl], rs = rsL[rl];
#pragma unroll
      for (int n = 0; n < 4; ++n) {
        float t = (acc[i][n][r] - mu) * rs * g4[n] + be4[n];
        outf[(size_t)row * 256 + colbase + n * 16] = t > 0.f ? t : 0.f;
      }
    }
}

// ---------------------------------------------------------------------------
// GAT aggregation, 3 branches in one dispatch (blockIdx.y = branch)
__global__ void gat3(const int* __restrict__ offs, const int* __restrict__ elist,
                     const float* __restrict__ s_all, const float* __restrict__ d_all,
                     const u16* __restrict__ h, const float* __restrict__ bg,
                     u16* __restrict__ xiall) {
  int b = blockIdx.y;
  const int* offs_b = offs + (size_t)b * (NN + 1);
  const int* elist_b = elist + (size_t)b * NE;
  const float* s = s_all + (size_t)b * NN;
  const float* d = d_all + (size_t)b * NN;
  const float* bgrow = bg + b * 256;
  int v = blockIdx.x * 4 + (threadIdx.x >> 6);
  int lane = threadIdx.x & 63;
  float dv = d[v], sv = s[v];
  float eself = lrelu(sv + dv);
  int beg = offs_b[v], end = offs_b[v + 1];
  float m = eself;
  for (int j = beg; j < end; ++j) m = fmaxf(m, lrelu(s[elist_b[j]] + dv));
  float denom = 0.f;
  float acc[4] = {0.f, 0.f, 0.f, 0.f};
  for (int j = beg; j < end; ++j) {
    int u = elist_b[j];
    float w = __expf(lrelu(s[u] + dv) - m);
    denom += w;
    u16x4 hv = *(const u16x4*)(h + (size_t)u * 768 + b * 256 + lane * 4);
#pragma unroll
    for (int k = 0; k < 4; ++k) acc[k] += w * b2f(hv[k]);
  }
  float wself = __expf(eself - m);
  denom += wself;
  u16x4 hv = *(const u16x4*)(h + (size_t)v * 768 + b * 256 + lane * 4);
#pragma unroll
  for (int k = 0; k < 4; ++k) acc[k] += wself * b2f(hv[k]);
  float inv = 1.0f / denom;
  f32x4 bg4 = *(const f32x4*)(bgrow + lane * 4);
  u16x4 outv;
#pragma unroll
  for (int k = 0; k < 4; ++k) outv[k] = f2b(acc[k] * inv + bg4[k]);
  *(u16x4*)(xiall + (size_t)v * 768 + b * 256 + lane * 4) = outv;
}

// ---------------------------------------------------------------------------
extern "C" void kernel_launch(void* const* d_in, const int* in_sizes, int n_in,
                              void* d_out, int out_size, void* d_ws, size_t ws_size,
                              hipStream_t stream) {
  const float* x   = (const float*)d_in[0];
  const int* ei    = (const int*)d_in[1];
  const int* ea    = (const int*)d_in[2];
  const float* Wg  = (const float*)d_in[3];
  const float* asrc= (const float*)d_in[4];
  const float* adst= (const float*)d_in[5];
  const float* bg  = (const float*)d_in[6];
  const float* Wsm = (const float*)d_in[7];
  const float* bs  = (const float*)d_in[8];
  const float* gs  = (const float*)d_in[9];
  const float* betas=(const float*)d_in[10];
  const float* W1  = (const float*)d_in[11];
  const float* b1  = (const float*)d_in[12];
  const float* W2  = (const float*)d_in[13];
  const float* b2  = (const float*)d_in[14];
  const float* Wf  = (const float*)d_in[15];
  const float* bfv = (const float*)d_in[16];
  const float* gf  = (const float*)d_in[17];
  const float* betaf=(const float*)d_in[18];
  float* out = (float*)d_out;

  char* wsb = (char*)d_ws;
  size_t off = 0;
  auto alloc = [&](size_t bytes) -> void* {
    void* p = wsb + off;
    off += bytes;
    off = (off + 255) & ~(size_t)255;
    return p;
  };
  int* flag    = (int*)alloc(sizeof(int));
  float* g_sum = (float*)alloc(256 * sizeof(float));
  float* sw    = (float*)alloc(4 * sizeof(float));
  int* counts  = (int*)alloc((size_t)3 * NN * sizeof(int));
  int* offs    = (int*)alloc((size_t)3 * (NN + 1) * sizeof(int));
  int* cur     = (int*)alloc((size_t)3 * NN * sizeof(int));
  int* bsum    = (int*)alloc((size_t)3 * NCHUNK * sizeof(int));
  int* bpre    = (int*)alloc((size_t)3 * NCHUNK * sizeof(int));
  int* srcE    = (int*)alloc((size_t)NE * sizeof(int));
  int* dstE    = (int*)alloc((size_t)NE * sizeof(int));
  int* attrE   = (int*)alloc((size_t)NE * sizeof(int));
  int* elist   = (int*)alloc((size_t)3 * NE * sizeof(int));
  float* s_arr = (float*)alloc((size_t)3 * NN * sizeof(float));
  float* d_arr = (float*)alloc((size_t)3 * NN * sizeof(float));
  u16* WT      = (u16*)alloc((size_t)8 * 65536 * sizeof(u16));
  u16* xb      = (u16*)alloc((size_t)NN * HH * sizeof(u16));
  u16* h768    = (u16*)alloc((size_t)NN * 768 * sizeof(u16));
  u16* xiall   = (u16*)alloc((size_t)NN * 768 * sizeof(u16));
  u16* comb    = (u16*)alloc((size_t)NN * HH * sizeof(u16));
  (void)ws_size; (void)in_sizes; (void)n_in; (void)out_size;

  hipMemsetAsync(flag, 0, sizeof(int), stream);
  hipMemsetAsync(g_sum, 0, 256 * sizeof(float), stream);
  hipMemsetAsync(counts, 0, (size_t)3 * NN * sizeof(int), stream);

  detect_kernel<<<1, 256, 0, stream>>>(ei, flag);
  norm_edges<<<(NE + 255) / 256, 256, 0, stream>>>(ei, ea, flag, srcE, dstE, attrE);

  transpose_all<<<dim3(8, 8, 8), dim3(32, 8), 0, stream>>>(Wg, Wsm, Wf, WT);
  xprep<<<1024, 256, 0, stream>>>(x, xb, g_sum);
  selector_kernel<<<1, 128, 0, stream>>>(g_sum, W1, b1, W2, b2, sw);

  hist_kernel<<<(NE + 255) / 256, 256, 0, stream>>>(dstE, attrE, counts);
  scan1<<<dim3(NCHUNK, 3), 256, 0, stream>>>(counts, offs, bsum);
  scan2<<<1, 64, 0, stream>>>(bsum, bpre, offs);
  scan3<<<dim3(NCHUNK, 3), 256, 0, stream>>>(bpre, offs, cur);
  scatter_kernel<<<(NE + 255) / 256, 256, 0, stream>>>(srcE, dstE, attrE, cur, elist);

  const int GB = (NN + 63) / 64;  // 782

  mgemm_h<<<dim3(GB, 3), 256, 0, stream>>>(xb, WT, asrc, adst, h768, s_arr, d_arr, NN);
  gat3<<<dim3(12500, 3), 256, 0, stream>>>(offs, elist, s_arr, d_arr, h768, bg, xiall);
  mgemm_ws<<<GB, 256, 0, stream>>>(xiall, xb, WT, bs, gs, betas, sw, comb, NN);
  mgemm_fin<<<GB, 256, 0, stream>>>(comb, WT + (size_t)7 * 65536, bfv, gf, betaf, out, NN);
}

// Round 6
// 461.998 us; speedup vs baseline: 1.1825x; 1.1825x over previous
//
#include <hip/hip_runtime.h>

typedef unsigned short u16;
typedef short s16x8 __attribute__((ext_vector_type(8)));
typedef float f32x4 __attribute__((ext_vector_type(4)));
typedef u16 u16x4 __attribute__((ext_vector_type(4)));

#define NN 50000
#define NE 300000
#define HH 256
#define NCHUNK 196
#define NXB 391          // ceil(50000/128) row-blocks of 128

__device__ __forceinline__ float b2f(u16 u) {
  union { float f; unsigned int i; } v; v.i = ((unsigned int)u) << 16; return v.f;
}
__device__ __forceinline__ u16 f2b(float f) {
  union { float f; unsigned int i; } v; v.f = f;
  unsigned int u = v.i;
  unsigned int r = (u + 0x7fffu + ((u >> 16) & 1u)) >> 16;
  return (u16)r;
}
__device__ __forceinline__ float lrelu(float x) { return x > 0.f ? x : 0.2f * x; }

#define GLOAD_LDS16(SRC, DST)                                                   \
  __builtin_amdgcn_global_load_lds(                                             \
      (const __attribute__((address_space(1))) void*)(SRC),                     \
      (__attribute__((address_space(3))) void*)(DST), 16, 0, 0)

__device__ __forceinline__ f32x4 MFMA(s16x8 a, s16x8 b, f32x4 c) {
  return __builtin_amdgcn_mfma_f32_16x16x32_bf16(a, b, c, 0, 0, 0);
}

// ---------------------------------------------------------------------------
// GEMM core: per block 4 waves x 32 rows = 128 rows, BN=256 (full), K=256.
// B^T (256x256 bf16, [n][k] rows of 512B) staged to LDS in two 64KB K-halves;
// LDS layout [col][128k] 256B rows with 16-slot XOR swizzle (slot ^= col&15),
// pre-swizzled on the global source (both-sides rule). A-fragments come
// straight from global memory into registers -- no barriers on the A path.
// FIX r5->r6: stage 64 x 1KB chunks per half (16 per wave), not 16.
template <typename AF>
__device__ __forceinline__ void gemm_core(AF af, const u16* __restrict__ BT,
                                          char* ldsB, f32x4 (&acc)[2][16],
                                          int lane, int wid) {
#pragma unroll
  for (int p = 0; p < 2; ++p) {
#pragma unroll
    for (int j = 0; j < 16; ++j) {
      int idx = j * 4 + wid;                 // 64 x 1KB chunks per half
      int g = idx * 1024 + lane * 16;        // linear LDS dest byte
      int col = g >> 8;                      // B^T row (output col)
      int slot = (g >> 4) & 15;              // 16B slot within 256B row
      GLOAD_LDS16((const char*)BT + col * 512 + p * 256 + ((slot ^ (col & 15)) << 4),
                  ldsB + idx * 1024);
    }
    __syncthreads();
#pragma unroll
    for (int ks = 0; ks < 4; ++ks) {
      int kel = p * 128 + ks * 32 + (lane >> 4) * 8;
      s16x8 a0 = af(0, kel);
      s16x8 a1 = af(1, kel);
      const char* bb = ldsB + (lane & 15) * 256 +
                       (((ks * 4 + (lane >> 4)) ^ (lane & 15)) << 4);
#pragma unroll
      for (int nf = 0; nf < 16; ++nf) {
        s16x8 bf = *(const s16x8*)(bb + nf * 4096);
        acc[0][nf] = MFMA(a0, bf, acc[0][nf]);
        acc[1][nf] = MFMA(a1, bf, acc[1][nf]);
      }
    }
    __syncthreads();
  }
}

// ---------------------------------------------------------------------------
// h-GEMM: 3 branches, XCD-chunked decode so same-row blocks of all 3 branches
// run on the same XCD (A-rows L2-hot). Fused s/d row-dots + contiguous h write.
__global__ __launch_bounds__(256) void hgemm(
    const u16* __restrict__ xb, const u16* __restrict__ WT,
    const float* __restrict__ asrc, const float* __restrict__ adst,
    u16* __restrict__ h768, float* __restrict__ s_arr, float* __restrict__ d_arr,
    int M) {
  __shared__ __align__(16) char ldsB[65536];
  int cid = blockIdx.x;                      // grid = 1176 (8*147)
  int j = (cid & 7) * 147 + (cid >> 3);
  if (j >= NXB * 3) return;
  int x = j / 3, b = j - x * 3;
  int tid = threadIdx.x, lane = tid & 63, wid = tid >> 6;
  int rowbase = x * 128 + wid * 32;
  int ar0 = rowbase + (lane & 15); if (ar0 > M - 1) ar0 = M - 1;
  int ar1 = ar0 + 16; if (ar1 > M - 1) ar1 = M - 1;

  f32x4 acc[2][16] = {};
  auto af = [&](int i, int kel) {
    return *(const s16x8*)(xb + (size_t)(i ? ar1 : ar0) * 256 + kel);
  };
  gemm_core(af, WT + (size_t)b * 65536, ldsB, acc, lane, wid);

  const float* av = asrc + b * 256;
  const float* dv = adst + b * 256;
  float a4[16], dd4[16];
#pragma unroll
  for (int nf = 0; nf < 16; ++nf) {
    a4[nf] = av[(lane & 15) + nf * 16];
    dd4[nf] = dv[(lane & 15) + nf * 16];
  }
#pragma unroll
  for (int i = 0; i < 2; ++i)
#pragma unroll
    for (int r = 0; r < 4; ++r) {
      float sp = 0.f, dp = 0.f;
#pragma unroll
      for (int nf = 0; nf < 16; ++nf) {
        float v = acc[i][nf][r];
        sp += v * a4[nf]; dp += v * dd4[nf];
      }
#pragma unroll
      for (int m = 1; m < 16; m <<= 1) { sp += __shfl_xor(sp, m); dp += __shfl_xor(dp, m); }
      int row = rowbase + i * 16 + (lane >> 4) * 4 + r;
      if ((lane & 15) == 0 && row < M) {
        s_arr[(size_t)b * NN + row] = sp;
        d_arr[(size_t)b * NN + row] = dp;
      }
    }
  // bounce acc -> LDS (wave-private 16KB) -> contiguous 512B-per-row stores
  char* le = ldsB + wid * 16384;
#pragma unroll
  for (int i = 0; i < 2; ++i)
#pragma unroll
    for (int r = 0; r < 4; ++r) {
      int lrow = i * 16 + (lane >> 4) * 4 + r;
#pragma unroll
      for (int nf = 0; nf < 16; ++nf)
        *(u16*)(le + lrow * 512 + ((lane & 15) + nf * 16) * 2) = f2b(acc[i][nf][r]);
    }
  __syncthreads();
#pragma unroll
  for (int jj = 0; jj < 16; ++jj) {
    int lrow = jj * 2 + (lane >> 5);
    int row = rowbase + lrow;
    if (row < M)
      *(s16x8*)((char*)h768 + (size_t)row * 1536 + b * 512 + (lane & 31) * 16) =
          *(const s16x8*)(le + jj * 1024 + lane * 16);
  }
}

// ---------------------------------------------------------------------------
// ws-GEMM: 4 branches fully parallel (grid 1564). Epilogue: +bias, LN (wave-
// internal 16-lane reduce), relu, x sw[b], bf16 -> ybuf[b] (pre-scaled slice).
__global__ __launch_bounds__(256) void wsgemm(
    const u16* __restrict__ xiall, const u16* __restrict__ xb,
    const u16* __restrict__ WT, const float* __restrict__ bs,
    const float* __restrict__ gs, const float* __restrict__ betas,
    const float* __restrict__ sw, u16* __restrict__ ybuf, int M) {
  __shared__ __align__(16) char ldsB[65536];
  int cid = blockIdx.x;
  int b = cid & 3, x = cid >> 2;
  int tid = threadIdx.x, lane = tid & 63, wid = tid >> 6;
  int rowbase = x * 128 + wid * 32;
  int ar0 = rowbase + (lane & 15); if (ar0 > M - 1) ar0 = M - 1;
  int ar1 = ar0 + 16; if (ar1 > M - 1) ar1 = M - 1;

  const u16* Ap = (b < 3) ? xiall : xb;
  size_t stride = (b < 3) ? 768 : 256;
  int coloff = (b < 3) ? b * 256 : 0;

  f32x4 acc[2][16] = {};
  auto af = [&](int i, int kel) {
    return *(const s16x8*)(Ap + (size_t)(i ? ar1 : ar0) * stride + coloff + kel);
  };
  gemm_core(af, WT + (size_t)(3 + b) * 65536, ldsB, acc, lane, wid);

  float g4[16], be4[16], bv4[16];
#pragma unroll
  for (int nf = 0; nf < 16; ++nf) {
    int c = (lane & 15) + nf * 16;
    bv4[nf] = bs[b * 256 + c];
    g4[nf] = gs[b * 256 + c];
    be4[nf] = betas[b * 256 + c];
  }
  float w = sw[b];
  char* le = ldsB + wid * 16384;
#pragma unroll
  for (int i = 0; i < 2; ++i)
#pragma unroll
    for (int r = 0; r < 4; ++r) {
      float s = 0.f, q = 0.f;
#pragma unroll
      for (int nf = 0; nf < 16; ++nf) {
        float v = acc[i][nf][r] + bv4[nf];
        acc[i][nf][r] = v;
        s += v; q += v * v;
      }
#pragma unroll
      for (int m = 1; m < 16; m <<= 1) { s += __shfl_xor(s, m); q += __shfl_xor(q, m); }
      float mu = s * (1.0f / HH);
      float var = q * (1.0f / HH) - mu * mu;
      float rs = rsqrtf(var + 1e-5f);
      int lrow = i * 16 + (lane >> 4) * 4 + r;
#pragma unroll
      for (int nf = 0; nf < 16; ++nf) {
        float t = (acc[i][nf][r] - mu) * rs * g4[nf] + be4[nf];
        t = t > 0.f ? t : 0.f;
        *(u16*)(le + lrow * 512 + ((lane & 15) + nf * 16) * 2) = f2b(w * t);
      }
    }
  __syncthreads();
  u16* yb = ybuf + (size_t)b * NN * 256;
#pragma unroll
  for (int jj = 0; jj < 16; ++jj) {
    int lrow = jj * 2 + (lane >> 5);
    int row = rowbase + lrow;
    if (row < M)
      *(s16x8*)((char*)yb + (size_t)row * 512 + (lane & 31) * 16) =
          *(const s16x8*)(le + jj * 1024 + lane * 16);
  }
}

// ---------------------------------------------------------------------------
// fin: A = sum of 4 pre-scaled ybuf slices (on-the-fly); out = relu(LN(A@Wf+bf)) f32
__global__ __launch_bounds__(256) void fingemm(
    const u16* __restrict__ ybuf, const u16* __restrict__ WT7,
    const float* __restrict__ bfv, const float* __restrict__ gf,
    const float* __restrict__ betaf, float* __restrict__ outf, int M) {
  __shared__ __align__(16) char ldsB[65536];
  int x = blockIdx.x;
  int tid = threadIdx.x, lane = tid & 63, wid = tid >> 6;
  int rowbase = x * 128 + wid * 32;
  int ar0 = rowbase + (lane & 15); if (ar0 > M - 1) ar0 = M - 1;
  int ar1 = ar0 + 16; if (ar1 > M - 1) ar1 = M - 1;
  const u16* y0 = ybuf;
  const u16* y1 = ybuf + (size_t)NN * 256;
  const u16* y2 = ybuf + (size_t)2 * NN * 256;
  const u16* y3 = ybuf + (size_t)3 * NN * 256;

  f32x4 acc[2][16] = {};
  auto af = [&](int i, int kel) {
    size_t o = (size_t)(i ? ar1 : ar0) * 256 + kel;
    s16x8 v0 = *(const s16x8*)(y0 + o);
    s16x8 v1 = *(const s16x8*)(y1 + o);
    s16x8 v2 = *(const s16x8*)(y2 + o);
    s16x8 v3 = *(const s16x8*)(y3 + o);
    s16x8 rr;
#pragma unroll
    for (int e = 0; e < 8; ++e)
      rr[e] = (short)f2b(b2f((u16)v0[e]) + b2f((u16)v1[e]) + b2f((u16)v2[e]) + b2f((u16)v3[e]));
    return rr;
  };
  gemm_core(af, WT7, ldsB, acc, lane, wid);

  float g4[16], be4[16], bv4[16];
#pragma unroll
  for (int nf = 0; nf < 16; ++nf) {
    int c = (lane & 15) + nf * 16;
    bv4[nf] = bfv[c]; g4[nf] = gf[c]; be4[nf] = betaf[c];
  }
  float* le = (float*)(ldsB + wid * 16384);  // 16 rows x 1KB per round
#pragma unroll
  for (int i = 0; i < 2; ++i) {
#pragma unroll
    for (int r = 0; r < 4; ++r) {
      float s = 0.f, q = 0.f;
#pragma unroll
      for (int nf = 0; nf < 16; ++nf) {
        float v = acc[i][nf][r] + bv4[nf];
        acc[i][nf][r] = v;
        s += v; q += v * v;
      }
#pragma unroll
      for (int m = 1; m < 16; m <<= 1) { s += __shfl_xor(s, m); q += __shfl_xor(q, m); }
      float mu = s * (1.0f / HH);
      float var = q * (1.0f / HH) - mu * mu;
      float rs = rsqrtf(var + 1e-5f);
      int sr = (lane >> 4) * 4 + r;
#pragma unroll
      for (int nf = 0; nf < 16; ++nf) {
        float t = (acc[i][nf][r] - mu) * rs * g4[nf] + be4[nf];
        le[sr * 256 + (lane & 15) + nf * 16] = t > 0.f ? t : 0.f;
      }
    }
    __syncthreads();
#pragma unroll
    for (int jj = 0; jj < 16; ++jj) {
      int row = rowbase + i * 16 + jj;
      if (row < M)
        *(f32x4*)(outf + (size_t)row * 256 + lane * 4) = *(const f32x4*)(le + jj * 256 + lane * 4);
    }
    __syncthreads();
  }
}

// ---------------------------------------------------------------------------
// xb = bf16(x); g_sum[c] += column sums
__global__ void xprep(const float* __restrict__ x, u16* __restrict__ xb,
                      float* __restrict__ g_sum) {
  int tid = threadIdx.x, lane = tid & 63, w = tid >> 6;
  f32x4 part = {0.f, 0.f, 0.f, 0.f};
  for (int r = blockIdx.x * 4 + w; r < NN; r += 4096) {
    f32x4 v = *(const f32x4*)(x + (size_t)r * HH + lane * 4);
    u16x4 o;
#pragma unroll
    for (int k = 0; k < 4; ++k) o[k] = f2b(v[k]);
    *(u16x4*)(xb + (size_t)r * HH + lane * 4) = o;
    part += v;
  }
  __shared__ f32x4 sh[256];
  sh[tid] = part;
  __syncthreads();
  if (tid < 64) {
    f32x4 t = sh[tid] + sh[tid + 64] + sh[tid + 128] + sh[tid + 192];
#pragma unroll
    for (int k = 0; k < 4; ++k) atomicAdd(&g_sum[lane * 4 + k], t[k]);
  }
}

// 8 weight transposes: WT[z][n][k] = bf16(src_z[k][n])
__global__ void transpose_all(const float* __restrict__ Wg, const float* __restrict__ Wsm,
                              const float* __restrict__ Wf, u16* __restrict__ WT) {
  __shared__ float tile[32][33];
  int z = blockIdx.z;
  const float* src = (z < 3) ? (Wg + (size_t)z * 65536)
                   : (z < 7) ? (Wsm + (size_t)(z - 3) * 65536) : Wf;
  u16* dst = WT + (size_t)z * 65536;
  int tx = threadIdx.x, ty = threadIdx.y;
  int bx = blockIdx.x, by = blockIdx.y;
#pragma unroll
  for (int j = 0; j < 32; j += 8)
    tile[ty + j][tx] = src[(size_t)(by * 32 + ty + j) * 256 + bx * 32 + tx];
  __syncthreads();
#pragma unroll
  for (int j = 0; j < 32; j += 8)
    dst[(size_t)(bx * 32 + ty + j) * 256 + by * 32 + tx] = f2b(tile[tx][ty + j]);
}

__global__ void selector_kernel(const float* __restrict__ g_sum,
                                const float* __restrict__ W1, const float* __restrict__ b1,
                                const float* __restrict__ W2, const float* __restrict__ b2,
                                float* __restrict__ sw) {
  __shared__ float gg[256];
  __shared__ float hid[128];
  __shared__ float lg[4];
  int t = threadIdx.x;  // 128
  gg[t] = g_sum[t] * (1.0f / NN);
  gg[t + 128] = g_sum[t + 128] * (1.0f / NN);
  __syncthreads();
  float a = 0.f;
  for (int c = 0; c < 256; ++c) a += gg[c] * W1[c * 128 + t];
  a += b1[t];
  hid[t] = a > 0.f ? a : 0.f;
  __syncthreads();
  if (t < 4) {
    float s = 0.f;
    for (int j = 0; j < 128; ++j) s += hid[j] * W2[j * 4 + t];
    lg[t] = s + b2[t];
  }
  __syncthreads();
  if (t == 0) {
    float m = fmaxf(fmaxf(lg[0], lg[1]), fmaxf(lg[2], lg[3]));
    float e0 = __expf(lg[0] - m), e1 = __expf(lg[1] - m);
    float e2 = __expf(lg[2] - m), e3 = __expf(lg[3] - m);
    float inv = 1.0f / (e0 + e1 + e2 + e3);
    sw[0] = e0 * inv; sw[1] = e1 * inv; sw[2] = e2 * inv; sw[3] = e3 * inv;
  }
}

// ---------------------------------------------------------------------------
__global__ void detect_kernel(const int* __restrict__ ei_raw, int* __restrict__ flag) {
  int t = threadIdx.x;
  int nz = 0;
  for (int k = t; k < 1024; k += 256) nz |= (ei_raw[2 * k + 1] != 0);
  if (nz) atomicOr(flag, 1);
}

__global__ void norm_edges(const int* __restrict__ ei_raw, const int* __restrict__ ea_raw,
                           const int* __restrict__ flag, int* __restrict__ srcE,
                           int* __restrict__ dstE, int* __restrict__ attrE) {
  int e = blockIdx.x * 256 + threadIdx.x;
  if (e >= NE) return;
  if (*flag) {
    srcE[e] = ei_raw[e];
    dstE[e] = ei_raw[NE + e];
    attrE[e] = ea_raw[e];
  } else {
    srcE[e] = ei_raw[2 * e];
    dstE[e] = ei_raw[2 * NE + 2 * e];
    attrE[e] = ea_raw[2 * e];
  }
}

__global__ void hist_kernel(const int* __restrict__ dstE, const int* __restrict__ attrE,
                            int* __restrict__ counts) {
  int e = blockIdx.x * 256 + threadIdx.x;
  if (e < NE) {
    int a = attrE[e];
    if ((unsigned)a < 3u) atomicAdd(&counts[a * NN + dstE[e]], 1);
  }
}

__global__ void scan1(const int* __restrict__ counts, int* __restrict__ offs,
                      int* __restrict__ bsum) {
  int b = blockIdx.y, c = blockIdx.x, t = threadIdx.x;
  int idx = c * 256 + t;
  int v = (idx < NN) ? counts[b * NN + idx] : 0;
  __shared__ int sh[256];
  sh[t] = v;
  __syncthreads();
  for (int o = 1; o < 256; o <<= 1) {
    int add = (t >= o) ? sh[t - o] : 0;
    __syncthreads();
    sh[t] += add;
    __syncthreads();
  }
  int incl = sh[t];
  if (idx < NN) offs[b * (NN + 1) + idx] = incl - v;
  if (t == 255) bsum[b * NCHUNK + c] = incl;
}

__global__ void scan2(const int* __restrict__ bsum, int* __restrict__ bpre,
                      int* __restrict__ offs) {
  int t = threadIdx.x;
  if (t < 3) {
    int run = 0;
    for (int c = 0; c < NCHUNK; ++c) { bpre[t * NCHUNK + c] = run; run += bsum[t * NCHUNK + c]; }
    offs[t * (NN + 1) + NN] = run;
  }
}

__global__ void scan3(const int* __restrict__ bpre, int* __restrict__ offs,
                      int* __restrict__ cur) {
  int b = blockIdx.y, c = blockIdx.x;
  int idx = c * 256 + threadIdx.x;
  if (idx < NN) {
    int val = offs[b * (NN + 1) + idx] + bpre[b * NCHUNK + c];
    offs[b * (NN + 1) + idx] = val;
    cur[b * NN + idx] = val;
  }
}

__global__ void scatter_kernel(const int* __restrict__ srcE, const int* __restrict__ dstE,
                               const int* __restrict__ attrE, int* __restrict__ cur,
                               int* __restrict__ elist) {
  int e = blockIdx.x * 256 + threadIdx.x;
  if (e < NE) {
    int a = attrE[e];
    if ((unsigned)a < 3u) {
      int p = atomicAdd(&cur[a * NN + dstE[e]], 1);
      elist[a * NE + p] = srcE[e];
    }
  }
}

// ---------------------------------------------------------------------------
// GAT aggregation, 3 branches in one dispatch
__global__ void gat3(const int* __restrict__ offs, const int* __restrict__ elist,
                     const float* __restrict__ s_all, const float* __restrict__ d_all,
                     const u16* __restrict__ h, const float* __restrict__ bg,
                     u16* __restrict__ xiall) {
  int b = blockIdx.y;
  const int* offs_b = offs + (size_t)b * (NN + 1);
  const int* elist_b = elist + (size_t)b * NE;
  const float* s = s_all + (size_t)b * NN;
  const float* d = d_all + (size_t)b * NN;
  const float* bgrow = bg + b * 256;
  int v = blockIdx.x * 4 + (threadIdx.x >> 6);
  int lane = threadIdx.x & 63;
  float dv = d[v], sv = s[v];
  float eself = lrelu(sv + dv);
  int beg = offs_b[v], end = offs_b[v + 1];
  float m = eself;
  for (int j = beg; j < end; ++j) m = fmaxf(m, lrelu(s[elist_b[j]] + dv));
  float denom = 0.f;
  float acc[4] = {0.f, 0.f, 0.f, 0.f};
  for (int j = beg; j < end; ++j) {
    int u = elist_b[j];
    float w = __expf(lrelu(s[u] + dv) - m);
    denom += w;
    u16x4 hv = *(const u16x4*)(h + (size_t)u * 768 + b * 256 + lane * 4);
#pragma unroll
    for (int k = 0; k < 4; ++k) acc[k] += w * b2f(hv[k]);
  }
  float wself = __expf(eself - m);
  denom += wself;
  u16x4 hv = *(const u16x4*)(h + (size_t)v * 768 + b * 256 + lane * 4);
#pragma unroll
  for (int k = 0; k < 4; ++k) acc[k] += wself * b2f(hv[k]);
  float inv = 1.0f / denom;
  f32x4 bg4 = *(const f32x4*)(bgrow + lane * 4);
  u16x4 outv;
#pragma unroll
  for (int k = 0; k < 4; ++k) outv[k] = f2b(acc[k] * inv + bg4[k]);
  *(u16x4*)(xiall + (size_t)v * 768 + b * 256 + lane * 4) = outv;
}

// ---------------------------------------------------------------------------
extern "C" void kernel_launch(void* const* d_in, const int* in_sizes, int n_in,
                              void* d_out, int out_size, void* d_ws, size_t ws_size,
                              hipStream_t stream) {
  const float* x   = (const float*)d_in[0];
  const int* ei    = (const int*)d_in[1];
  const int* ea    = (const int*)d_in[2];
  const float* Wg  = (const float*)d_in[3];
  const float* asrc= (const float*)d_in[4];
  const float* adst= (const float*)d_in[5];
  const float* bg  = (const float*)d_in[6];
  const float* Wsm = (const float*)d_in[7];
  const float* bs  = (const float*)d_in[8];
  const float* gs  = (const float*)d_in[9];
  const float* betas=(const float*)d_in[10];
  const float* W1  = (const float*)d_in[11];
  const float* b1  = (const float*)d_in[12];
  const float* W2  = (const float*)d_in[13];
  const float* b2  = (const float*)d_in[14];
  const float* Wf  = (const float*)d_in[15];
  const float* bfv = (const float*)d_in[16];
  const float* gf  = (const float*)d_in[17];
  const float* betaf=(const float*)d_in[18];
  float* out = (float*)d_out;

  char* wsb = (char*)d_ws;
  size_t off = 0;
  auto alloc = [&](size_t bytes) -> void* {
    void* p = wsb + off;
    off += bytes;
    off = (off + 255) & ~(size_t)255;
    return p;
  };
  int* flag    = (int*)alloc(sizeof(int));
  float* g_sum = (float*)alloc(256 * sizeof(float));
  float* sw    = (float*)alloc(4 * sizeof(float));
  int* counts  = (int*)alloc((size_t)3 * NN * sizeof(int));
  int* offs    = (int*)alloc((size_t)3 * (NN + 1) * sizeof(int));
  int* cur     = (int*)alloc((size_t)3 * NN * sizeof(int));
  int* bsum    = (int*)alloc((size_t)3 * NCHUNK * sizeof(int));
  int* bpre    = (int*)alloc((size_t)3 * NCHUNK * sizeof(int));
  int* srcE    = (int*)alloc((size_t)NE * sizeof(int));
  int* dstE    = (int*)alloc((size_t)NE * sizeof(int));
  int* attrE   = (int*)alloc((size_t)NE * sizeof(int));
  int* elist   = (int*)alloc((size_t)3 * NE * sizeof(int));
  float* s_arr = (float*)alloc((size_t)3 * NN * sizeof(float));
  float* d_arr = (float*)alloc((size_t)3 * NN * sizeof(float));
  u16* WT      = (u16*)alloc((size_t)8 * 65536 * sizeof(u16));
  u16* xb      = (u16*)alloc((size_t)NN * HH * sizeof(u16));
  // h768 (3x[NN][256] interleaved as [NN][768]) is dead after gat3; its 76.8MB
  // is reused as ybuf slices 0..2; ybuf3 allocated contiguously right after.
  u16* h768    = (u16*)alloc((size_t)NN * 768 * sizeof(u16));  // 76,800,000 B (256-aligned)
  u16* ybuf3   = (u16*)alloc((size_t)NN * 256 * sizeof(u16));
  u16* xiall   = (u16*)alloc((size_t)NN * 768 * sizeof(u16));
  u16* ybuf    = h768;  // 4 x [NN][256] consecutive (slice 3 = ybuf3)
  (void)ybuf3; (void)ws_size; (void)in_sizes; (void)n_in; (void)out_size;

  hipMemsetAsync(flag, 0, sizeof(int), stream);
  hipMemsetAsync(g_sum, 0, 256 * sizeof(float), stream);
  hipMemsetAsync(counts, 0, (size_t)3 * NN * sizeof(int), stream);

  detect_kernel<<<1, 256, 0, stream>>>(ei, flag);
  norm_edges<<<(NE + 255) / 256, 256, 0, stream>>>(ei, ea, flag, srcE, dstE, attrE);

  transpose_all<<<dim3(8, 8, 8), dim3(32, 8), 0, stream>>>(Wg, Wsm, Wf, WT);
  xprep<<<1024, 256, 0, stream>>>(x, xb, g_sum);
  selector_kernel<<<1, 128, 0, stream>>>(g_sum, W1, b1, W2, b2, sw);

  hist_kernel<<<(NE + 255) / 256, 256, 0, stream>>>(dstE, attrE, counts);
  scan1<<<dim3(NCHUNK, 3), 256, 0, stream>>>(counts, offs, bsum);
  scan2<<<1, 64, 0, stream>>>(bsum, bpre, offs);
  scan3<<<dim3(NCHUNK, 3), 256, 0, stream>>>(bpre, offs, cur);
  scatter_kernel<<<(NE + 255) / 256, 256, 0, stream>>>(srcE, dstE, attrE, cur, elist);

  hgemm<<<1176, 256, 0, stream>>>(xb, WT, asrc, adst, h768, s_arr, d_arr, NN);
  gat3<<<dim3(12500, 3), 256, 0, stream>>>(offs, elist, s_arr, d_arr, h768, bg, xiall);
  wsgemm<<<NXB * 4, 256, 0, stream>>>(xiall, xb, WT, bs, gs, betas, sw, ybuf, NN);
  fingemm<<<NXB, 256, 0, stream>>>(ybuf, WT + (size_t)7 * 65536, bfv, gf, betaf, out, NN);
}

// Round 9
// 446.202 us; speedup vs baseline: 1.2243x; 1.0354x over previous
//
#include <hip/hip_runtime.h>

typedef unsigned short u16;
typedef short s16x8 __attribute__((ext_vector_type(8)));
typedef float f32x4 __attribute__((ext_vector_type(4)));
typedef u16 u16x4 __attribute__((ext_vector_type(4)));

#define NN 50000
#define NE 300000
#define HH 256
#define NCHUNK 196
#define NXB 391          // ceil(50000/128) row-blocks of 128

__device__ __forceinline__ float b2f(u16 u) {
  union { float f; unsigned int i; } v; v.i = ((unsigned int)u) << 16; return v.f;
}
__device__ __forceinline__ u16 f2b(float f) {
  union { float f; unsigned int i; } v; v.f = f;
  unsigned int u = v.i;
  unsigned int r = (u + 0x7fffu + ((u >> 16) & 1u)) >> 16;
  return (u16)r;
}
__device__ __forceinline__ float lrelu(float x) { return x > 0.f ? x : 0.2f * x; }

#define GLOAD_LDS16(SRC, DST)                                                   \
  __builtin_amdgcn_global_load_lds(                                             \
      (const __attribute__((address_space(1))) void*)(SRC),                     \
      (__attribute__((address_space(3))) void*)(DST), 16, 0, 0)

__device__ __forceinline__ f32x4 MFMA(s16x8 a, s16x8 b, f32x4 c) {
  return __builtin_amdgcn_mfma_f32_16x16x32_bf16(a, b, c, 0, 0, 0);
}

// ---------------------------------------------------------------------------
// NEW (bisect target): B^T K-tile stage, 16KB = 256 cols x 64B (32 k-elems).
// Chunk c of col stored at slot s = c ^ (col&3) ^ ((col>>2)&3) (involution),
// applied via inverse-swizzled global source; linear LDS dest (rule #21).
__device__ __forceinline__ void stageB32(const u16* __restrict__ BT, int q,
                                         char* dst, int lane, int wid) {
#pragma unroll
  for (int j = 0; j < 4; ++j) {
    int idx = j * 4 + wid;                   // 16 x 1KB chunks per wave-set
    int g = idx * 1024 + lane * 16;
    int col = g >> 6;
    int s = (g >> 4) & 3;
    int c = s ^ (col & 3) ^ ((col >> 2) & 3);
    GLOAD_LDS16((const char*)BT + col * 512 + q * 64 + c * 16, dst + idx * 1024);
  }
}

// NEW (bisect target): 2-phase double-buffered core. 8 K-tiles of 32;
// stage(q+1) + A-prefetch(q+1) issued before compute(q); one barrier/tile.
// Uses first 32KB of the caller's 64KB LDS; rest untouched for epilogues.
template <typename AF>
__device__ __forceinline__ void gemm_core(AF af, const u16* __restrict__ BT,
                                          char* ldsB, f32x4 (&acc)[2][16],
                                          int lane, int wid) {
  int colL = lane & 15, cq = lane >> 4;
  int sL = cq ^ (colL & 3) ^ ((colL >> 2) & 3);
  stageB32(BT, 0, ldsB, lane, wid);
  s16x8 a0 = af(0, cq * 8), a1 = af(1, cq * 8);
  __syncthreads();
#pragma unroll
  for (int q = 0; q < 8; ++q) {
    s16x8 n0 = a0, n1 = a1;
    if (q < 7) {
      stageB32(BT, q + 1, ldsB + ((q + 1) & 1) * 16384, lane, wid);
      n0 = af(0, (q + 1) * 32 + cq * 8);
      n1 = af(1, (q + 1) * 32 + cq * 8);
    }
    const char* bb = ldsB + (q & 1) * 16384 + colL * 64 + sL * 16;
#pragma unroll
    for (int nf = 0; nf < 16; ++nf) {
      s16x8 bf = *(const s16x8*)(bb + nf * 1024);
      acc[0][nf] = MFMA(a0, bf, acc[0][nf]);
      acc[1][nf] = MFMA(a1, bf, acc[1][nf]);
    }
    a0 = n0; a1 = n1;
    __syncthreads();
  }
}

// ---------------------------------------------------------------------------
// h-GEMM: 3 branches, XCD-chunked decode; fused s/d row-dots; contiguous h
// writes via 16KB/wave LDS bounce (round-6 verbatim).
__global__ __launch_bounds__(256) void hgemm(
    const u16* __restrict__ xb, const u16* __restrict__ WT,
    const float* __restrict__ asrc, const float* __restrict__ adst,
    u16* __restrict__ h768, float* __restrict__ s_arr, float* __restrict__ d_arr,
    int M) {
  __shared__ __align__(16) char ldsB[65536];
  int cid = blockIdx.x;                      // grid = 1176 (8*147)
  int j = (cid & 7) * 147 + (cid >> 3);
  if (j >= NXB * 3) return;
  int x = j / 3, b = j - x * 3;
  int tid = threadIdx.x, lane = tid & 63, wid = tid >> 6;
  int rowbase = x * 128 + wid * 32;
  int ar0 = rowbase + (lane & 15); if (ar0 > M - 1) ar0 = M - 1;
  int ar1 = ar0 + 16; if (ar1 > M - 1) ar1 = M - 1;

  f32x4 acc[2][16] = {};
  auto af = [&](int i, int kel) {
    return *(const s16x8*)(xb + (size_t)(i ? ar1 : ar0) * 256 + kel);
  };
  gemm_core(af, WT + (size_t)b * 65536, ldsB, acc, lane, wid);

  const float* av = asrc + b * 256;
  const float* dv = adst + b * 256;
  float a4[16], dd4[16];
#pragma unroll
  for (int nf = 0; nf < 16; ++nf) {
    a4[nf] = av[(lane & 15) + nf * 16];
    dd4[nf] = dv[(lane & 15) + nf * 16];
  }
#pragma unroll
  for (int i = 0; i < 2; ++i)
#pragma unroll
    for (int r = 0; r < 4; ++r) {
      float sp = 0.f, dp = 0.f;
#pragma unroll
      for (int nf = 0; nf < 16; ++nf) {
        float v = acc[i][nf][r];
        sp += v * a4[nf]; dp += v * dd4[nf];
      }
#pragma unroll
      for (int m = 1; m < 16; m <<= 1) { sp += __shfl_xor(sp, m); dp += __shfl_xor(dp, m); }
      int row = rowbase + i * 16 + (lane >> 4) * 4 + r;
      if ((lane & 15) == 0 && row < M) {
        s_arr[(size_t)b * NN + row] = sp;
        d_arr[(size_t)b * NN + row] = dp;
      }
    }
  // bounce acc -> LDS (wave-private 16KB) -> contiguous 512B-per-row stores
  char* le = ldsB + wid * 16384;
#pragma unroll
  for (int i = 0; i < 2; ++i)
#pragma unroll
    for (int r = 0; r < 4; ++r) {
      int lrow = i * 16 + (lane >> 4) * 4 + r;
#pragma unroll
      for (int nf = 0; nf < 16; ++nf)
        *(u16*)(le + lrow * 512 + ((lane & 15) + nf * 16) * 2) = f2b(acc[i][nf][r]);
    }
  __syncthreads();
#pragma unroll
  for (int jj = 0; jj < 16; ++jj) {
    int lrow = jj * 2 + (lane >> 5);
    int row = rowbase + lrow;
    if (row < M)
      *(s16x8*)((char*)h768 + (size_t)row * 1536 + b * 512 + (lane & 31) * 16) =
          *(const s16x8*)(le + jj * 1024 + lane * 16);
  }
}

// ---------------------------------------------------------------------------
// ws-GEMM: 4 branches fully parallel (grid 1564); +bias, LN, relu, x sw[b].
__global__ __launch_bounds__(256) void wsgemm(
    const u16* __restrict__ xiall, const u16* __restrict__ xb,
    const u16* __restrict__ WT, const float* __restrict__ bs,
    const float* __restrict__ gs, const float* __restrict__ betas,
    const float* __restrict__ sw, u16* __restrict__ ybuf, int M) {
  __shared__ __align__(16) char ldsB[65536];
  int cid = blockIdx.x;
  int b = cid & 3, x = cid >> 2;
  int tid = threadIdx.x, lane = tid & 63, wid = tid >> 6;
  int rowbase = x * 128 + wid * 32;
  int ar0 = rowbase + (lane & 15); if (ar0 > M - 1) ar0 = M - 1;
  int ar1 = ar0 + 16; if (ar1 > M - 1) ar1 = M - 1;

  const u16* Ap = (b < 3) ? xiall : xb;
  size_t stride = (b < 3) ? 768 : 256;
  int coloff = (b < 3) ? b * 256 : 0;

  f32x4 acc[2][16] = {};
  auto af = [&](int i, int kel) {
    return *(const s16x8*)(Ap + (size_t)(i ? ar1 : ar0) * stride + coloff + kel);
  };
  gemm_core(af, WT + (size_t)(3 + b) * 65536, ldsB, acc, lane, wid);

  float g4[16], be4[16], bv4[16];
#pragma unroll
  for (int nf = 0; nf < 16; ++nf) {
    int c = (lane & 15) + nf * 16;
    bv4[nf] = bs[b * 256 + c];
    g4[nf] = gs[b * 256 + c];
    be4[nf] = betas[b * 256 + c];
  }
  float w = sw[b];
  char* le = ldsB + wid * 16384;
#pragma unroll
  for (int i = 0; i < 2; ++i)
#pragma unroll
    for (int r = 0; r < 4; ++r) {
      float s = 0.f, q = 0.f;
#pragma unroll
      for (int nf = 0; nf < 16; ++nf) {
        float v = acc[i][nf][r] + bv4[nf];
        acc[i][nf][r] = v;
        s += v; q += v * v;
      }
#pragma unroll
      for (int m = 1; m < 16; m <<= 1) { s += __shfl_xor(s, m); q += __shfl_xor(q, m); }
      float mu = s * (1.0f / HH);
      float var = q * (1.0f / HH) - mu * mu;
      float rs = rsqrtf(var + 1e-5f);
      int lrow = i * 16 + (lane >> 4) * 4 + r;
#pragma unroll
      for (int nf = 0; nf < 16; ++nf) {
        float t = (acc[i][nf][r] - mu) * rs * g4[nf] + be4[nf];
        t = t > 0.f ? t : 0.f;
        *(u16*)(le + lrow * 512 + ((lane & 15) + nf * 16) * 2) = f2b(w * t);
      }
    }
  __syncthreads();
  u16* yb = ybuf + (size_t)b * NN * 256;
#pragma unroll
  for (int jj = 0; jj < 16; ++jj) {
    int lrow = jj * 2 + (lane >> 5);
    int row = rowbase + lrow;
    if (row < M)
      *(s16x8*)((char*)yb + (size_t)row * 512 + (lane & 31) * 16) =
          *(const s16x8*)(le + jj * 1024 + lane * 16);
  }
}

// ---------------------------------------------------------------------------
// fin: A = sum of 4 pre-scaled ybuf slices (on-the-fly); out = relu(LN(A@Wf+bf)) f32
__global__ __launch_bounds__(256) void fingemm(
    const u16* __restrict__ ybuf, const u16* __restrict__ WT7,
    const float* __restrict__ bfv, const float* __restrict__ gf,
    const float* __restrict__ betaf, float* __restrict__ outf, int M) {
  __shared__ __align__(16) char ldsB[65536];
  int x = blockIdx.x;
  int tid = threadIdx.x, lane = tid & 63, wid = tid >> 6;
  int rowbase = x * 128 + wid * 32;
  int ar0 = rowbase + (lane & 15); if (ar0 > M - 1) ar0 = M - 1;
  int ar1 = ar0 + 16; if (ar1 > M - 1) ar1 = M - 1;
  const u16* y0 = ybuf;
  const u16* y1 = ybuf + (size_t)NN * 256;
  const u16* y2 = ybuf + (size_t)2 * NN * 256;
  const u16* y3 = ybuf + (size_t)3 * NN * 256;

  f32x4 acc[2][16] = {};
  auto af = [&](int i, int kel) {
    size_t o = (size_t)(i ? ar1 : ar0) * 256 + kel;
    s16x8 v0 = *(const s16x8*)(y0 + o);
    s16x8 v1 = *(const s16x8*)(y1 + o);
    s16x8 v2 = *(const s16x8*)(y2 + o);
    s16x8 v3 = *(const s16x8*)(y3 + o);
    s16x8 rr;
#pragma unroll
    for (int e = 0; e < 8; ++e)
      rr[e] = (short)f2b(b2f((u16)v0[e]) + b2f((u16)v1[e]) + b2f((u16)v2[e]) + b2f((u16)v3[e]));
    return rr;
  };
  gemm_core(af, WT7, ldsB, acc, lane, wid);

  float g4[16], be4[16], bv4[16];
#pragma unroll
  for (int nf = 0; nf < 16; ++nf) {
    int c = (lane & 15) + nf * 16;
    bv4[nf] = bfv[c]; g4[nf] = gf[c]; be4[nf] = betaf[c];
  }
  float* le = (float*)(ldsB + wid * 16384);  // 16 rows x 1KB per round
#pragma unroll
  for (int i = 0; i < 2; ++i) {
#pragma unroll
    for (int r = 0; r < 4; ++r) {
      float s = 0.f, q = 0.f;
#pragma unroll
      for (int nf = 0; nf < 16; ++nf) {
        float v = acc[i][nf][r] + bv4[nf];
        acc[i][nf][r] = v;
        s += v; q += v * v;
      }
#pragma unroll
      for (int m = 1; m < 16; m <<= 1) { s += __shfl_xor(s, m); q += __shfl_xor(q, m); }
      float mu = s * (1.0f / HH);
      float var = q * (1.0f / HH) - mu * mu;
      float rs = rsqrtf(var + 1e-5f);
      int sr = (lane >> 4) * 4 + r;
#pragma unroll
      for (int nf = 0; nf < 16; ++nf) {
        float t = (acc[i][nf][r] - mu) * rs * g4[nf] + be4[nf];
        le[sr * 256 + (lane & 15) + nf * 16] = t > 0.f ? t : 0.f;
      }
    }
    __syncthreads();
#pragma unroll
    for (int jj = 0; jj < 16; ++jj) {
      int row = rowbase + i * 16 + jj;
      if (row < M)
        *(f32x4*)(outf + (size_t)row * 256 + lane * 4) = *(const f32x4*)(le + jj * 256 + lane * 4);
    }
    __syncthreads();
  }
}

// ---------------------------------------------------------------------------
// xb = bf16(x); g_sum[c] += column sums
__global__ void xprep(const float* __restrict__ x, u16* __restrict__ xb,
                      float* __restrict__ g_sum) {
  int tid = threadIdx.x, lane = tid & 63, w = tid >> 6;
  f32x4 part = {0.f, 0.f, 0.f, 0.f};
  for (int r = blockIdx.x * 4 + w; r < NN; r += 4096) {
    f32x4 v = *(const f32x4*)(x + (size_t)r * HH + lane * 4);
    u16x4 o;
#pragma unroll
    for (int k = 0; k < 4; ++k) o[k] = f2b(v[k]);
    *(u16x4*)(xb + (size_t)r * HH + lane * 4) = o;
    part += v;
  }
  __shared__ f32x4 sh[256];
  sh[tid] = part;
  __syncthreads();
  if (tid < 64) {
    f32x4 t = sh[tid] + sh[tid + 64] + sh[tid + 128] + sh[tid + 192];
#pragma unroll
    for (int k = 0; k < 4; ++k) atomicAdd(&g_sum[lane * 4 + k], t[k]);
  }
}

// 8 weight transposes: WT[z][n][k] = bf16(src_z[k][n])
__global__ void transpose_all(const float* __restrict__ Wg, const float* __restrict__ Wsm,
                              const float* __restrict__ Wf, u16* __restrict__ WT) {
  __shared__ float tile[32][33];
  int z = blockIdx.z;
  const float* src = (z < 3) ? (Wg + (size_t)z * 65536)
                   : (z < 7) ? (Wsm + (size_t)(z - 3) * 65536) : Wf;
  u16* dst = WT + (size_t)z * 65536;
  int tx = threadIdx.x, ty = threadIdx.y;
  int bx = blockIdx.x, by = blockIdx.y;
#pragma unroll
  for (int j = 0; j < 32; j += 8)
    tile[ty + j][tx] = src[(size_t)(by * 32 + ty + j) * 256 + bx * 32 + tx];
  __syncthreads();
#pragma unroll
  for (int j = 0; j < 32; j += 8)
    dst[(size_t)(bx * 32 + ty + j) * 256 + by * 32 + tx] = f2b(tile[tx][ty + j]);
}

__global__ void selector_kernel(const float* __restrict__ g_sum,
                                const float* __restrict__ W1, const float* __restrict__ b1,
                                const float* __restrict__ W2, const float* __restrict__ b2,
                                float* __restrict__ sw) {
  __shared__ float gg[256];
  __shared__ float hid[128];
  __shared__ float lg[4];
  int t = threadIdx.x;  // 128
  gg[t] = g_sum[t] * (1.0f / NN);
  gg[t + 128] = g_sum[t + 128] * (1.0f / NN);
  __syncthreads();
  float a = 0.f;
  for (int c = 0; c < 256; ++c) a += gg[c] * W1[c * 128 + t];
  a += b1[t];
  hid[t] = a > 0.f ? a : 0.f;
  __syncthreads();
  if (t < 4) {
    float s = 0.f;
    for (int j = 0; j < 128; ++j) s += hid[j] * W2[j * 4 + t];
    lg[t] = s + b2[t];
  }
  __syncthreads();
  if (t == 0) {
    float m = fmaxf(fmaxf(lg[0], lg[1]), fmaxf(lg[2], lg[3]));
    float e0 = __expf(lg[0] - m), e1 = __expf(lg[1] - m);
    float e2 = __expf(lg[2] - m), e3 = __expf(lg[3] - m);
    float inv = 1.0f / (e0 + e1 + e2 + e3);
    sw[0] = e0 * inv; sw[1] = e1 * inv; sw[2] = e2 * inv; sw[3] = e3 * inv;
  }
}

// ---------------------------------------------------------------------------
__global__ void detect_kernel(const int* __restrict__ ei_raw, int* __restrict__ flag) {
  int t = threadIdx.x;
  int nz = 0;
  for (int k = t; k < 1024; k += 256) nz |= (ei_raw[2 * k + 1] != 0);
  if (nz) atomicOr(flag, 1);
}

__global__ void norm_edges(const int* __restrict__ ei_raw, const int* __restrict__ ea_raw,
                           const int* __restrict__ flag, int* __restrict__ srcE,
                           int* __restrict__ dstE, int* __restrict__ attrE) {
  int e = blockIdx.x * 256 + threadIdx.x;
  if (e >= NE) return;
  if (*flag) {
    srcE[e] = ei_raw[e];
    dstE[e] = ei_raw[NE + e];
    attrE[e] = ea_raw[e];
  } else {
    srcE[e] = ei_raw[2 * e];
    dstE[e] = ei_raw[2 * NE + 2 * e];
    attrE[e] = ea_raw[2 * e];
  }
}

__global__ void hist_kernel(const int* __restrict__ dstE, const int* __restrict__ attrE,
                            int* __restrict__ counts) {
  int e = blockIdx.x * 256 + threadIdx.x;
  if (e < NE) {
    int a = attrE[e];
    if ((unsigned)a < 3u) atomicAdd(&counts[a * NN + dstE[e]], 1);
  }
}

__global__ void scan1(const int* __restrict__ counts, int* __restrict__ offs,
                      int* __restrict__ bsum) {
  int b = blockIdx.y, c = blockIdx.x, t = threadIdx.x;
  int idx = c * 256 + t;
  int v = (idx < NN) ? counts[b * NN + idx] : 0;
  __shared__ int sh[256];
  sh[t] = v;
  __syncthreads();
  for (int o = 1; o < 256; o <<= 1) {
    int add = (t >= o) ? sh[t - o] : 0;
    __syncthreads();
    sh[t] += add;
    __syncthreads();
  }
  int incl = sh[t];
  if (idx < NN) offs[b * (NN + 1) + idx] = incl - v;
  if (t == 255) bsum[b * NCHUNK + c] = incl;
}

__global__ void scan2(const int* __restrict__ bsum, int* __restrict__ bpre,
                      int* __restrict__ offs) {
  int t = threadIdx.x;
  if (t < 3) {
    int run = 0;
    for (int c = 0; c < NCHUNK; ++c) { bpre[t * NCHUNK + c] = run; run += bsum[t * NCHUNK + c]; }
    offs[t * (NN + 1) + NN] = run;
  }
}

__global__ void scan3(const int* __restrict__ bpre, int* __restrict__ offs,
                      int* __restrict__ cur) {
  int b = blockIdx.y, c = blockIdx.x;
  int idx = c * 256 + threadIdx.x;
  if (idx < NN) {
    int val = offs[b * (NN + 1) + idx] + bpre[b * NCHUNK + c];
    offs[b * (NN + 1) + idx] = val;
    cur[b * NN + idx] = val;
  }
}

__global__ void scatter_kernel(const int* __restrict__ srcE, const int* __restrict__ dstE,
                               const int* __restrict__ attrE, int* __restrict__ cur,
                               int* __restrict__ elist) {
  int e = blockIdx.x * 256 + threadIdx.x;
  if (e < NE) {
    int a = attrE[e];
    if ((unsigned)a < 3u) {
      int p = atomicAdd(&cur[a * NN + dstE[e]], 1);
      elist[a * NE + p] = srcE[e];
    }
  }
}

// ---------------------------------------------------------------------------
// GAT aggregation, 3 branches in one dispatch (round-6 verbatim, serial gather)
__global__ void gat3(const int* __restrict__ offs, const int* __restrict__ elist,
                     const float* __restrict__ s_all, const float* __restrict__ d_all,
                     const u16* __restrict__ h, const float* __restrict__ bg,
                     u16* __restrict__ xiall) {
  int b = blockIdx.y;
  const int* offs_b = offs + (size_t)b * (NN + 1);
  const int* elist_b = elist + (size_t)b * NE;
  const float* s = s_all + (size_t)b * NN;
  const float* d = d_all + (size_t)b * NN;
  const float* bgrow = bg + b * 256;
  int v = blockIdx.x * 4 + (threadIdx.x >> 6);
  int lane = threadIdx.x & 63;
  float dv = d[v], sv = s[v];
  float eself = lrelu(sv + dv);
  int beg = offs_b[v], end = offs_b[v + 1];
  float m = eself;
  for (int j = beg; j < end; ++j) m = fmaxf(m, lrelu(s[elist_b[j]] + dv));
  float denom = 0.f;
  float acc[4] = {0.f, 0.f, 0.f, 0.f};
  for (int j = beg; j < end; ++j) {
    int u = elist_b[j];
    float w = __expf(lrelu(s[u] + dv) - m);
    denom += w;
    u16x4 hv = *(const u16x4*)(h + (size_t)u * 768 + b * 256 + lane * 4);
#pragma unroll
    for (int k = 0; k < 4; ++k) acc[k] += w * b2f(hv[k]);
  }
  float wself = __expf(eself - m);
  denom += wself;
  u16x4 hv = *(const u16x4*)(h + (size_t)v * 768 + b * 256 + lane * 4);
#pragma unroll
  for (int k = 0; k < 4; ++k) acc[k] += wself * b2f(hv[k]);
  float inv = 1.0f / denom;
  f32x4 bg4 = *(const f32x4*)(bgrow + lane * 4);
  u16x4 outv;
#pragma unroll
  for (int k = 0; k < 4; ++k) outv[k] = f2b(acc[k] * inv + bg4[k]);
  *(u16x4*)(xiall + (size_t)v * 768 + b * 256 + lane * 4) = outv;
}

// ---------------------------------------------------------------------------
extern "C" void kernel_launch(void* const* d_in, const int* in_sizes, int n_in,
                              void* d_out, int out_size, void* d_ws, size_t ws_size,
                              hipStream_t stream) {
  const float* x   = (const float*)d_in[0];
  const int* ei    = (const int*)d_in[1];
  const int* ea    = (const int*)d_in[2];
  const float* Wg  = (const float*)d_in[3];
  const float* asrc= (const float*)d_in[4];
  const float* adst= (const float*)d_in[5];
  const float* bg  = (const float*)d_in[6];
  const float* Wsm = (const float*)d_in[7];
  const float* bs  = (const float*)d_in[8];
  const float* gs  = (const float*)d_in[9];
  const float* betas=(const float*)d_in[10];
  const float* W1  = (const float*)d_in[11];
  const float* b1  = (const float*)d_in[12];
  const float* W2  = (const float*)d_in[13];
  const float* b2  = (const float*)d_in[14];
  const float* Wf  = (const float*)d_in[15];
  const float* bfv = (const float*)d_in[16];
  const float* gf  = (const float*)d_in[17];
  const float* betaf=(const float*)d_in[18];
  float* out = (float*)d_out;

  char* wsb = (char*)d_ws;
  size_t off = 0;
  auto alloc = [&](size_t bytes) -> void* {
    void* p = wsb + off;
    off += bytes;
    off = (off + 255) & ~(size_t)255;
    return p;
  };
  int* flag    = (int*)alloc(sizeof(int));
  float* g_sum = (float*)alloc(256 * sizeof(float));
  float* sw    = (float*)alloc(4 * sizeof(float));
  int* counts  = (int*)alloc((size_t)3 * NN * sizeof(int));
  int* offs    = (int*)alloc((size_t)3 * (NN + 1) * sizeof(int));
  int* cur     = (int*)alloc((size_t)3 * NN * sizeof(int));
  int* bsum    = (int*)alloc((size_t)3 * NCHUNK * sizeof(int));
  int* bpre    = (int*)alloc((size_t)3 * NCHUNK * sizeof(int));
  int* srcE    = (int*)alloc((size_t)NE * sizeof(int));
  int* dstE    = (int*)alloc((size_t)NE * sizeof(int));
  int* attrE   = (int*)alloc((size_t)NE * sizeof(int));
  int* elist   = (int*)alloc((size_t)3 * NE * sizeof(int));
  float* s_arr = (float*)alloc((size_t)3 * NN * sizeof(float));
  float* d_arr = (float*)alloc((size_t)3 * NN * sizeof(float));
  u16* WT      = (u16*)alloc((size_t)8 * 65536 * sizeof(u16));
  u16* xb      = (u16*)alloc((size_t)NN * HH * sizeof(u16));
  u16* h768    = (u16*)alloc((size_t)NN * 768 * sizeof(u16));  // reused as ybuf 0..2
  u16* ybuf3   = (u16*)alloc((size_t)NN * 256 * sizeof(u16));
  u16* xiall   = (u16*)alloc((size_t)NN * 768 * sizeof(u16));
  u16* ybuf    = h768;  // 4 slices consecutive (slice 3 = ybuf3)
  (void)ybuf3; (void)ws_size; (void)in_sizes; (void)n_in; (void)out_size;

  hipMemsetAsync(flag, 0, sizeof(int), stream);
  hipMemsetAsync(g_sum, 0, 256 * sizeof(float), stream);
  hipMemsetAsync(counts, 0, (size_t)3 * NN * sizeof(int), stream);

  detect_kernel<<<1, 256, 0, stream>>>(ei, flag);
  norm_edges<<<(NE + 255) / 256, 256, 0, stream>>>(ei, ea, flag, srcE, dstE, attrE);

  transpose_all<<<dim3(8, 8, 8), dim3(32, 8), 0, stream>>>(Wg, Wsm, Wf, WT);
  xprep<<<1024, 256, 0, stream>>>(x, xb, g_sum);
  selector_kernel<<<1, 128, 0, stream>>>(g_sum, W1, b1, W2, b2, sw);

  hist_kernel<<<(NE + 255) / 256, 256, 0, stream>>>(dstE, attrE, counts);
  scan1<<<dim3(NCHUNK, 3), 256, 0, stream>>>(counts, offs, bsum);
  scan2<<<1, 64, 0, stream>>>(bsum, bpre, offs);
  scan3<<<dim3(NCHUNK, 3), 256, 0, stream>>>(bpre, offs, cur);
  scatter_kernel<<<(NE + 255) / 256, 256, 0, stream>>>(srcE, dstE, attrE, cur, elist);

  hgemm<<<1176, 256, 0, stream>>>(xb, WT, asrc, adst, h768, s_arr, d_arr, NN);
  gat3<<<dim3(12500, 3), 256, 0, stream>>>(offs, elist, s_arr, d_arr, h768, bg, xiall);
  wsgemm<<<NXB * 4, 256, 0, stream>>>(xiall, xb, WT, bs, gs, betas, sw, ybuf, NN);
  fingemm<<<NXB, 256, 0, stream>>>(ybuf, WT + (size_t)7 * 65536, bfv, gf, betaf, out, NN);
}